// Round 1
// baseline (2520.151 us; speedup 1.0000x reference)
//
#include <hip/hip_runtime.h>
#include <hip/hip_bf16.h>

// SpikingLayer: T=64 sequential LIF steps, each a dense 8192x8192 fp32 matvec
// cur = W @ f  followed by  v' = 0.9*v + cur; fire = v' >= 1; reset on fire.
// Output layout (flat): fires[T][N] at offset 0, vs[T][N] at offset T*N.

#define N_NEURONS 8192
#define T_STEPS   64
#define DECAY     0.9f
#define THRESH    1.0f

// ws layout (floats): v[N], fbuf0[N], fbuf1[N]
__global__ __launch_bounds__(256) void init_state(const float* __restrict__ f0,
                                                  const float* __restrict__ v0,
                                                  float* __restrict__ v,
                                                  float* __restrict__ fbuf0) {
    int i = blockIdx.x * 256 + threadIdx.x;
    if (i < N_NEURONS) {
        v[i] = v0[i];
        fbuf0[i] = f0[i];
    }
}

// One wave (64 lanes) computes one row's dot product. 4 rows per block.
// f (current firing state, 8192 fp32 = 32 KB) is staged into LDS once per block.
__global__ __launch_bounds__(256) void step_kernel(const float* __restrict__ W,
                                                   const float* __restrict__ fin,
                                                   float* __restrict__ fout,
                                                   float* __restrict__ v,
                                                   float* __restrict__ out_fire,
                                                   float* __restrict__ out_v) {
    __shared__ float fs[N_NEURONS];

    // Stage f into LDS, vectorized: 2048 float4 across 256 threads = 8 iters.
    const float4* f4 = (const float4*)fin;
    float4* fs4 = (float4*)fs;
    #pragma unroll
    for (int k = 0; k < N_NEURONS / 4 / 256; ++k) {
        fs4[k * 256 + threadIdx.x] = f4[k * 256 + threadIdx.x];
    }
    __syncthreads();

    const int wave = threadIdx.x >> 6;
    const int lane = threadIdx.x & 63;
    const int row  = blockIdx.x * 4 + wave;

    const float4* Wrow = (const float4*)(W + (size_t)row * N_NEURONS);

    // Each lane: 32 float4 loads, stride 64 float4s (coalesced 1 KiB/instr/wave).
    float acc = 0.f;
    #pragma unroll 8
    for (int k = 0; k < N_NEURONS / 4 / 64; ++k) {
        const int idx = k * 64 + lane;
        float4 w = Wrow[idx];
        float4 f = fs4[idx];
        acc += w.x * f.x + w.y * f.y + w.z * f.z + w.w * f.w;
    }

    // Butterfly reduce across the 64-lane wave.
    #pragma unroll
    for (int off = 32; off > 0; off >>= 1) acc += __shfl_down(acc, off);

    if (lane == 0) {
        float vn   = DECAY * v[row] + acc;
        float fire = (vn >= THRESH) ? 1.0f : 0.0f;
        out_fire[row] = fire;
        out_v[row]    = vn;                       // pre-reset potential
        fout[row]     = fire;
        v[row]        = (fire > 0.f) ? 0.f : vn;  // reset on fire
    }
}

extern "C" void kernel_launch(void* const* d_in, const int* in_sizes, int n_in,
                              void* d_out, int out_size, void* d_ws, size_t ws_size,
                              hipStream_t stream) {
    // setup_inputs order: x [T,N] (unused), W [N,N], f0 [N], v0 [N]
    const float* W  = (const float*)d_in[1];
    const float* f0 = (const float*)d_in[2];
    const float* v0 = (const float*)d_in[3];
    float* out = (float*)d_out;

    float* v     = (float*)d_ws;
    float* fbuf0 = v + N_NEURONS;
    float* fbuf1 = fbuf0 + N_NEURONS;

    init_state<<<(N_NEURONS + 255) / 256, 256, 0, stream>>>(f0, v0, v, fbuf0);

    float* fbufs[2] = {fbuf0, fbuf1};
    for (int t = 0; t < T_STEPS; ++t) {
        const float* fin = fbufs[t & 1];
        float* fout      = fbufs[(t + 1) & 1];
        float* out_fire  = out + (size_t)t * N_NEURONS;
        float* out_v     = out + (size_t)T_STEPS * N_NEURONS + (size_t)t * N_NEURONS;
        step_kernel<<<N_NEURONS / 4, 256, 0, stream>>>(W, fin, fout, v, out_fire, out_v);
    }
}

// Round 2
// 991.833 us; speedup vs baseline: 2.5409x; 2.5409x over previous
//
#include <hip/hip_runtime.h>
#include <hip/hip_bf16.h>

// SpikingLayer: T=64 sequential LIF steps. cur = W @ f with W ~11% dense
// (distance mask). Strategy: build CSR (u16 col + f32 val) once per launch,
// then 64 sparse matvec steps. CSR (~47 MB) stays resident in Infinity Cache.
// Output layout (flat): fires[T][N] at 0, vs[T][N] at T*N.

#define N_NEURONS 8192
#define T_STEPS   64
#define DECAY     0.9f
#define THRESH    1.0f
#define NNZ_CAP   9437184u  // 14.06% density cap; actual ~11-12.6%

// ws byte layout:
//   v      @ 0        (8192 f32)
//   fb0    @ 32768    (8192 f32)
//   fb1    @ 65536    (8192 f32)
//   rowptr @ 98304    (8193 u32)
//   val    @ 131088   (NNZ_CAP f32)
//   col    @ 131088 + NNZ_CAP*4  (NNZ_CAP u16)
#define WS_ROWPTR_OFF 98304
#define WS_VAL_OFF    131088
#define WS_REQUIRED   (WS_VAL_OFF + (size_t)NNZ_CAP * 6)

__global__ __launch_bounds__(256) void init_state(const float* __restrict__ f0,
                                                  const float* __restrict__ v0,
                                                  float* __restrict__ v,
                                                  float* __restrict__ fbuf0) {
    int i = blockIdx.x * 256 + threadIdx.x;
    if (i < N_NEURONS) {
        v[i] = v0[i];
        fbuf0[i] = f0[i];
    }
}

// ---- CSR build ----

// Wave per row: count nonzeros (coalesced float4 strided reads).
__global__ __launch_bounds__(256) void count_rows(const float* __restrict__ W,
                                                  unsigned* __restrict__ rowptr) {
    const int wave = threadIdx.x >> 6, lane = threadIdx.x & 63;
    const int row = blockIdx.x * 4 + wave;
    const float4* Wr = (const float4*)(W + (size_t)row * N_NEURONS);
    int c = 0;
    #pragma unroll 8
    for (int k = 0; k < N_NEURONS / 4 / 64; ++k) {
        float4 w = Wr[k * 64 + lane];
        c += (w.x != 0.f) + (w.y != 0.f) + (w.z != 0.f) + (w.w != 0.f);
    }
    #pragma unroll
    for (int off = 32; off; off >>= 1) c += __shfl_down(c, off);
    if (lane == 0) rowptr[row + 1] = (unsigned)c;
}

// Single block: exclusive scan of per-row counts, each padded up to EVEN
// (so every row's CSR segment is 8B-aligned for float2/uint loads).
__global__ __launch_bounds__(1024) void scan_rows(unsigned* __restrict__ rowptr) {
    __shared__ unsigned part[1024];
    const int t = threadIdx.x;
    unsigned c[8], s = 0;
    #pragma unroll
    for (int i = 0; i < 8; ++i) {
        c[i] = (rowptr[t * 8 + i + 1] + 1u) & ~1u;  // round up to even
        s += c[i];
    }
    part[t] = s;
    __syncthreads();
    // Hillis-Steele inclusive scan over 1024 partials.
    for (int off = 1; off < 1024; off <<= 1) {
        unsigned add = (t >= off) ? part[t - off] : 0u;
        __syncthreads();
        part[t] += add;
        __syncthreads();
    }
    unsigned base = part[t] - s;  // exclusive
    if (t == 0) rowptr[0] = 0;
    #pragma unroll
    for (int i = 0; i < 8; ++i) {
        base += c[i];
        rowptr[t * 8 + i + 1] = base;
    }
}

// Wave per row: each lane owns a contiguous 128-column chunk, wave-scan for
// lane offsets, write (val,col) in column order. Pads odd rows with a zero.
__global__ __launch_bounds__(256) void fill_csr(const float* __restrict__ W,
                                                const unsigned* __restrict__ rowptr,
                                                float* __restrict__ val,
                                                unsigned short* __restrict__ col) {
    const int wave = threadIdx.x >> 6, lane = threadIdx.x & 63;
    const int row = blockIdx.x * 4 + wave;
    const float4* Wr = (const float4*)(W + (size_t)row * N_NEURONS);

    int c = 0;
    #pragma unroll 8
    for (int k = 0; k < 32; ++k) {
        float4 w = Wr[lane * 32 + k];
        c += (w.x != 0.f) + (w.y != 0.f) + (w.z != 0.f) + (w.w != 0.f);
    }
    // inclusive wave scan
    int incl = c;
    #pragma unroll
    for (int off = 1; off < 64; off <<= 1) {
        int n = __shfl_up(incl, off);
        if (lane >= off) incl += n;
    }
    const int total = __shfl(incl, 63);
    unsigned p = rowptr[row] + (unsigned)(incl - c);

    #pragma unroll 4
    for (int k = 0; k < 32; ++k) {
        float4 w = Wr[lane * 32 + k];
        int cb = lane * 128 + k * 4;
        if (w.x != 0.f) { val[p] = w.x; col[p] = (unsigned short)(cb);     ++p; }
        if (w.y != 0.f) { val[p] = w.y; col[p] = (unsigned short)(cb + 1); ++p; }
        if (w.z != 0.f) { val[p] = w.z; col[p] = (unsigned short)(cb + 2); ++p; }
        if (w.w != 0.f) { val[p] = w.w; col[p] = (unsigned short)(cb + 3); ++p; }
    }
    if (lane == 63) {
        unsigned end = rowptr[row + 1];
        if (rowptr[row] + (unsigned)total < end) {  // at most one pad slot
            unsigned q = rowptr[row] + (unsigned)total;
            val[q] = 0.f; col[q] = 0;
        }
    }
}

// ---- Sparse step: 16 waves/block, wave per row, f staged in LDS ----
__global__ __launch_bounds__(1024) void step_csr(const unsigned* __restrict__ rowptr,
                                                 const float* __restrict__ val,
                                                 const unsigned short* __restrict__ col,
                                                 const float* __restrict__ fin,
                                                 float* __restrict__ fout,
                                                 float* __restrict__ v,
                                                 float* __restrict__ out_fire,
                                                 float* __restrict__ out_v) {
    __shared__ float fs[N_NEURONS];
    const float4* f4 = (const float4*)fin;
    float4* fs4 = (float4*)fs;
    #pragma unroll
    for (int k = 0; k < N_NEURONS / 4 / 1024; ++k)
        fs4[k * 1024 + threadIdx.x] = f4[k * 1024 + threadIdx.x];
    __syncthreads();

    const int wave = threadIdx.x >> 6, lane = threadIdx.x & 63;
    const int row = blockIdx.x * 16 + wave;
    const unsigned start = rowptr[row], end = rowptr[row + 1];

    float acc = 0.f;
    for (unsigned k = start + (unsigned)lane * 2; k < end; k += 128) {
        float2 w = *(const float2*)(val + k);          // 8B aligned (start even)
        unsigned cc = *(const unsigned*)(col + k);     // two u16 cols
        acc += w.x * fs[cc & 0xffffu] + w.y * fs[cc >> 16];
    }
    #pragma unroll
    for (int off = 32; off; off >>= 1) acc += __shfl_down(acc, off);

    if (lane == 0) {
        float vn   = DECAY * v[row] + acc;
        float fire = (vn >= THRESH) ? 1.0f : 0.0f;
        out_fire[row] = fire;
        out_v[row]    = vn;
        fout[row]     = fire;
        v[row]        = (fire > 0.f) ? 0.f : vn;
    }
}

// ---- Dense fallback (round-1 kernel) if ws is too small for CSR ----
__global__ __launch_bounds__(256) void step_dense(const float* __restrict__ W,
                                                  const float* __restrict__ fin,
                                                  float* __restrict__ fout,
                                                  float* __restrict__ v,
                                                  float* __restrict__ out_fire,
                                                  float* __restrict__ out_v) {
    __shared__ float fs[N_NEURONS];
    const float4* f4 = (const float4*)fin;
    float4* fs4 = (float4*)fs;
    #pragma unroll
    for (int k = 0; k < N_NEURONS / 4 / 256; ++k)
        fs4[k * 256 + threadIdx.x] = f4[k * 256 + threadIdx.x];
    __syncthreads();

    const int wave = threadIdx.x >> 6, lane = threadIdx.x & 63;
    const int row = blockIdx.x * 4 + wave;
    const float4* Wrow = (const float4*)(W + (size_t)row * N_NEURONS);

    float acc = 0.f;
    #pragma unroll 8
    for (int k = 0; k < N_NEURONS / 4 / 64; ++k) {
        const int idx = k * 64 + lane;
        float4 w = Wrow[idx];
        float4 f = fs4[idx];
        acc += w.x * f.x + w.y * f.y + w.z * f.z + w.w * f.w;
    }
    #pragma unroll
    for (int off = 32; off; off >>= 1) acc += __shfl_down(acc, off);

    if (lane == 0) {
        float vn   = DECAY * v[row] + acc;
        float fire = (vn >= THRESH) ? 1.0f : 0.0f;
        out_fire[row] = fire;
        out_v[row]    = vn;
        fout[row]     = fire;
        v[row]        = (fire > 0.f) ? 0.f : vn;
    }
}

extern "C" void kernel_launch(void* const* d_in, const int* in_sizes, int n_in,
                              void* d_out, int out_size, void* d_ws, size_t ws_size,
                              hipStream_t stream) {
    // inputs: x [T,N] (unused), W [N,N], f0 [N], v0 [N]
    const float* W  = (const float*)d_in[1];
    const float* f0 = (const float*)d_in[2];
    const float* v0 = (const float*)d_in[3];
    float* out = (float*)d_out;

    char* ws = (char*)d_ws;
    float* v      = (float*)ws;
    float* fb0    = (float*)(ws + 32768);
    float* fb1    = (float*)(ws + 65536);
    unsigned* rowptr     = (unsigned*)(ws + WS_ROWPTR_OFF);
    float* val           = (float*)(ws + WS_VAL_OFF);
    unsigned short* col  = (unsigned short*)(ws + WS_VAL_OFF + (size_t)NNZ_CAP * 4);

    init_state<<<(N_NEURONS + 255) / 256, 256, 0, stream>>>(f0, v0, v, fb0);

    float* fbufs[2] = {fb0, fb1};

    if (ws_size >= WS_REQUIRED) {
        count_rows<<<N_NEURONS / 4, 256, 0, stream>>>(W, rowptr);
        scan_rows<<<1, 1024, 0, stream>>>(rowptr);
        fill_csr<<<N_NEURONS / 4, 256, 0, stream>>>(W, rowptr, val, col);
        for (int t = 0; t < T_STEPS; ++t) {
            const float* fin = fbufs[t & 1];
            float* fout      = fbufs[(t + 1) & 1];
            step_csr<<<N_NEURONS / 16, 1024, 0, stream>>>(
                rowptr, val, col, fin, fout, v,
                out + (size_t)t * N_NEURONS,
                out + (size_t)(T_STEPS + t) * N_NEURONS);
        }
    } else {
        for (int t = 0; t < T_STEPS; ++t) {
            const float* fin = fbufs[t & 1];
            float* fout      = fbufs[(t + 1) & 1];
            step_dense<<<N_NEURONS / 4, 256, 0, stream>>>(
                W, fin, fout, v,
                out + (size_t)t * N_NEURONS,
                out + (size_t)(T_STEPS + t) * N_NEURONS);
        }
    }
}

// Round 3
// 783.891 us; speedup vs baseline: 3.2149x; 1.2653x over previous
//
#include <hip/hip_runtime.h>
#include <hip/hip_bf16.h>

// SpikingLayer: T=64 sequential LIF steps. cur = W @ f with W ~12% dense.
// Build CSR (u16 col + f32 val) once per launch with fully coalesced W reads,
// then 64 sparse steps. Firing state kept as an 8192-bit mask (f is 0/1, so
// the matvec is a conditional add). CSR (~51 MB) stays L3-resident.
// Output layout (flat): fires[T][N] at 0, vs[T][N] at T*N.

#define N_NEURONS 8192
#define T_STEPS   64
#define DECAY     0.9f
#define THRESH    1.0f
#define NNZ_CAP   9437184u  // 14.06% density cap; actual ~12.3%
#define STAGE_CAP 1536      // max nnz/row ~1150 (mean 1030, sigma ~31)

// ws byte layout:
//   v      @ 0       (8192 f32)
//   fb0    @ 32768   (8192 f32, dense fallback only)
//   fb1    @ 65536   (8192 f32, dense fallback only)
//   m0     @ 98304   (1024 B bitmask)
//   m1     @ 99328   (1024 B bitmask)
//   rowptr @ 100352  (8193 u32)
//   val    @ 133632  (NNZ_CAP f32)
//   col    @ 133632 + NNZ_CAP*4  (NNZ_CAP u16)
#define WS_M0_OFF     98304
#define WS_M1_OFF     99328
#define WS_ROWPTR_OFF 100352
#define WS_VAL_OFF    133632
#define WS_REQUIRED   (WS_VAL_OFF + (size_t)NNZ_CAP * 6)

__global__ __launch_bounds__(256) void init_state(const float* __restrict__ f0,
                                                  const float* __restrict__ v0,
                                                  float* __restrict__ v,
                                                  float* __restrict__ fbuf0,
                                                  unsigned char* __restrict__ m0) {
    int i = blockIdx.x * 256 + threadIdx.x;
    if (i < N_NEURONS) {
        v[i] = v0[i];
        fbuf0[i] = f0[i];
    }
    if (i < N_NEURONS / 8) {
        unsigned b = 0;
        #pragma unroll
        for (int j = 0; j < 8; ++j) b |= (f0[i * 8 + j] != 0.f ? 1u : 0u) << j;
        m0[i] = (unsigned char)b;
    }
}

// ---- CSR build ----

// Wave per row: count nonzeros (coalesced float4 strided reads).
__global__ __launch_bounds__(256) void count_rows(const float* __restrict__ W,
                                                  unsigned* __restrict__ rowptr) {
    const int wave = threadIdx.x >> 6, lane = threadIdx.x & 63;
    const int row = blockIdx.x * 4 + wave;
    const float4* Wr = (const float4*)(W + (size_t)row * N_NEURONS);
    int c = 0;
    #pragma unroll 8
    for (int k = 0; k < N_NEURONS / 4 / 64; ++k) {
        float4 w = Wr[k * 64 + lane];
        c += (w.x != 0.f) + (w.y != 0.f) + (w.z != 0.f) + (w.w != 0.f);
    }
    #pragma unroll
    for (int off = 32; off; off >>= 1) c += __shfl_down(c, off);
    if (lane == 0) rowptr[row + 1] = (unsigned)c;
}

// Single block: exclusive scan of per-row counts, each padded up to EVEN
// (so every row's CSR segment is 8B-aligned for float2/uint loads).
__global__ __launch_bounds__(1024) void scan_rows(unsigned* __restrict__ rowptr) {
    __shared__ unsigned part[1024];
    const int t = threadIdx.x;
    unsigned c[8], s = 0;
    #pragma unroll
    for (int i = 0; i < 8; ++i) {
        c[i] = (rowptr[t * 8 + i + 1] + 1u) & ~1u;  // round up to even
        s += c[i];
    }
    part[t] = s;
    __syncthreads();
    for (int off = 1; off < 1024; off <<= 1) {
        unsigned add = (t >= off) ? part[t - off] : 0u;
        __syncthreads();
        part[t] += add;
        __syncthreads();
    }
    unsigned base = part[t] - s;  // exclusive
    if (t == 0) rowptr[0] = 0;
    #pragma unroll
    for (int i = 0; i < 8; ++i) {
        base += c[i];
        rowptr[t * 8 + i + 1] = base;
    }
}

// Wave per row, COALESCED reads (lane-interleaved float4), ballot-compaction
// into per-wave LDS staging, then coalesced copy-out. Column order preserved.
__global__ __launch_bounds__(256) void fill_csr(const float* __restrict__ W,
                                                const unsigned* __restrict__ rowptr,
                                                float* __restrict__ val,
                                                unsigned short* __restrict__ col) {
    __shared__ float          sval[4][STAGE_CAP];
    __shared__ unsigned short scol[4][STAGE_CAP];

    const int wave = threadIdx.x >> 6, lane = threadIdx.x & 63;
    const int row = blockIdx.x * 4 + wave;
    const float4* Wr = (const float4*)(W + (size_t)row * N_NEURONS);
    const unsigned long long lt = ((unsigned long long)1 << lane) - 1;

    unsigned base = 0;  // wave-uniform running nnz
    for (int k = 0; k < 32; ++k) {
        const int idx = k * 64 + lane;
        float4 w = Wr[idx];
        const int c0 = idx * 4;
        unsigned long long m;
        m = __ballot(w.x != 0.f);
        if (w.x != 0.f) { unsigned p = base + (unsigned)__popcll(m & lt); sval[wave][p] = w.x; scol[wave][p] = (unsigned short)c0; }
        base += (unsigned)__popcll(m);
        m = __ballot(w.y != 0.f);
        if (w.y != 0.f) { unsigned p = base + (unsigned)__popcll(m & lt); sval[wave][p] = w.y; scol[wave][p] = (unsigned short)(c0 + 1); }
        base += (unsigned)__popcll(m);
        m = __ballot(w.z != 0.f);
        if (w.z != 0.f) { unsigned p = base + (unsigned)__popcll(m & lt); sval[wave][p] = w.z; scol[wave][p] = (unsigned short)(c0 + 2); }
        base += (unsigned)__popcll(m);
        m = __ballot(w.w != 0.f);
        if (w.w != 0.f) { unsigned p = base + (unsigned)__popcll(m & lt); sval[wave][p] = w.w; scol[wave][p] = (unsigned short)(c0 + 3); }
        base += (unsigned)__popcll(m);
    }

    const unsigned rs = rowptr[row];
    const unsigned n  = rowptr[row + 1] - rs;  // padded (== base or base+1)
    if (lane == 0 && base < n) { sval[wave][base] = 0.f; scol[wave][base] = 0; }
    __syncthreads();

    for (unsigned i = lane; i < n; i += 64) {
        val[rs + i] = sval[wave][i];
        col[rs + i] = scol[wave][i];
    }
}

// ---- Sparse step: 8 waves/block, wave per row, firing mask (1 KB) in LDS ----
__global__ __launch_bounds__(512) void step_bits(const unsigned* __restrict__ rowptr,
                                                 const float* __restrict__ val,
                                                 const unsigned short* __restrict__ col,
                                                 const unsigned* __restrict__ min_mask,
                                                 unsigned char* __restrict__ mout,
                                                 float* __restrict__ v,
                                                 float* __restrict__ out_fire,
                                                 float* __restrict__ out_v) {
    __shared__ unsigned bits[N_NEURONS / 32];  // 1 KB
    __shared__ float flags[8];

    if (threadIdx.x < N_NEURONS / 32) bits[threadIdx.x] = min_mask[threadIdx.x];
    __syncthreads();

    const int wave = threadIdx.x >> 6, lane = threadIdx.x & 63;
    const int row = blockIdx.x * 8 + wave;
    const unsigned start = rowptr[row], end = rowptr[row + 1];

    float acc = 0.f;
    for (unsigned k = start + (unsigned)lane * 2; k < end; k += 128) {
        float2 w = *(const float2*)(val + k);       // 8B aligned (start even)
        unsigned cc = *(const unsigned*)(col + k);  // two u16 cols
        unsigned c0 = cc & 0xffffu, c1 = cc >> 16;
        if ((bits[c0 >> 5] >> (c0 & 31)) & 1u) acc += w.x;
        if ((bits[c1 >> 5] >> (c1 & 31)) & 1u) acc += w.y;
    }
    #pragma unroll
    for (int off = 32; off; off >>= 1) acc += __shfl_down(acc, off);

    if (lane == 0) {
        float vn   = DECAY * v[row] + acc;
        float fire = (vn >= THRESH) ? 1.0f : 0.0f;
        out_fire[row] = fire;
        out_v[row]    = vn;
        v[row]        = (fire > 0.f) ? 0.f : vn;
        flags[wave]   = fire;
    }
    __syncthreads();
    if (threadIdx.x == 0) {
        unsigned b = 0;
        #pragma unroll
        for (int i = 0; i < 8; ++i) b |= (flags[i] > 0.f ? 1u : 0u) << i;
        mout[blockIdx.x] = (unsigned char)b;
    }
}

// ---- Dense fallback if ws is too small for CSR ----
__global__ __launch_bounds__(256) void step_dense(const float* __restrict__ W,
                                                  const float* __restrict__ fin,
                                                  float* __restrict__ fout,
                                                  float* __restrict__ v,
                                                  float* __restrict__ out_fire,
                                                  float* __restrict__ out_v) {
    __shared__ float fs[N_NEURONS];
    const float4* f4 = (const float4*)fin;
    float4* fs4 = (float4*)fs;
    #pragma unroll
    for (int k = 0; k < N_NEURONS / 4 / 256; ++k)
        fs4[k * 256 + threadIdx.x] = f4[k * 256 + threadIdx.x];
    __syncthreads();

    const int wave = threadIdx.x >> 6, lane = threadIdx.x & 63;
    const int row = blockIdx.x * 4 + wave;
    const float4* Wrow = (const float4*)(W + (size_t)row * N_NEURONS);

    float acc = 0.f;
    #pragma unroll 8
    for (int k = 0; k < N_NEURONS / 4 / 64; ++k) {
        const int idx = k * 64 + lane;
        float4 w = Wrow[idx];
        float4 f = fs4[idx];
        acc += w.x * f.x + w.y * f.y + w.z * f.z + w.w * f.w;
    }
    #pragma unroll
    for (int off = 32; off; off >>= 1) acc += __shfl_down(acc, off);

    if (lane == 0) {
        float vn   = DECAY * v[row] + acc;
        float fire = (vn >= THRESH) ? 1.0f : 0.0f;
        out_fire[row] = fire;
        out_v[row]    = vn;
        fout[row]     = fire;
        v[row]        = (fire > 0.f) ? 0.f : vn;
    }
}

extern "C" void kernel_launch(void* const* d_in, const int* in_sizes, int n_in,
                              void* d_out, int out_size, void* d_ws, size_t ws_size,
                              hipStream_t stream) {
    // inputs: x [T,N] (unused), W [N,N], f0 [N], v0 [N]
    const float* W  = (const float*)d_in[1];
    const float* f0 = (const float*)d_in[2];
    const float* v0 = (const float*)d_in[3];
    float* out = (float*)d_out;

    char* ws = (char*)d_ws;
    float* v   = (float*)ws;
    float* fb0 = (float*)(ws + 32768);
    float* fb1 = (float*)(ws + 65536);
    unsigned char* m0 = (unsigned char*)(ws + WS_M0_OFF);
    unsigned char* m1 = (unsigned char*)(ws + WS_M1_OFF);
    unsigned* rowptr    = (unsigned*)(ws + WS_ROWPTR_OFF);
    float* val          = (float*)(ws + WS_VAL_OFF);
    unsigned short* col = (unsigned short*)(ws + WS_VAL_OFF + (size_t)NNZ_CAP * 4);

    init_state<<<(N_NEURONS + 255) / 256, 256, 0, stream>>>(f0, v0, v, fb0, m0);

    if (ws_size >= WS_REQUIRED) {
        count_rows<<<N_NEURONS / 4, 256, 0, stream>>>(W, rowptr);
        scan_rows<<<1, 1024, 0, stream>>>(rowptr);
        fill_csr<<<N_NEURONS / 4, 256, 0, stream>>>(W, rowptr, val, col);
        unsigned char* masks[2] = {m0, m1};
        for (int t = 0; t < T_STEPS; ++t) {
            const unsigned* min_mask = (const unsigned*)masks[t & 1];
            unsigned char* mout      = masks[(t + 1) & 1];
            step_bits<<<N_NEURONS / 8, 512, 0, stream>>>(
                rowptr, val, col, min_mask, mout, v,
                out + (size_t)t * N_NEURONS,
                out + (size_t)(T_STEPS + t) * N_NEURONS);
        }
    } else {
        float* fbufs[2] = {fb0, fb1};
        for (int t = 0; t < T_STEPS; ++t) {
            const float* fin = fbufs[t & 1];
            float* fout      = fbufs[(t + 1) & 1];
            step_dense<<<N_NEURONS / 4, 256, 0, stream>>>(
                W, fin, fout, v,
                out + (size_t)t * N_NEURONS,
                out + (size_t)(T_STEPS + t) * N_NEURONS);
        }
    }
}